// Round 9
// baseline (334.786 us; speedup 1.0000x reference)
//
#include <hip/hip_runtime.h>
#include <stdint.h>
#include <stddef.h>

#define Bd 2
#define Sd 2048
#define Ed 2048
#define Hd 16
#define Dd 128

typedef unsigned short u16;
typedef _Float16 f16;
typedef __attribute__((ext_vector_type(8))) _Float16 half8;
typedef __attribute__((ext_vector_type(4))) float f32x4;

__device__ __forceinline__ u16 f2h(float f) {
  f16 h = (f16)f; return __builtin_bit_cast(u16, h);
}
__device__ __forceinline__ void gll16(const void* g, void* lds) {
  __builtin_amdgcn_global_load_lds(
      (const __attribute__((address_space(1))) void*)g,
      (__attribute__((address_space(3))) void*)lds, 16, 0, 0);
}
template<int C> __device__ __forceinline__ float dppmv(float x) {
  return __builtin_bit_cast(float,
      __builtin_amdgcn_update_dpp(0, __builtin_bit_cast(int, x), C, 0xF, 0xF, false));
}
__device__ __forceinline__ float rmax16(float x) {
  x = fmaxf(x, dppmv<0x121>(x)); x = fmaxf(x, dppmv<0x122>(x));
  x = fmaxf(x, dppmv<0x124>(x)); x = fmaxf(x, dppmv<0x128>(x));
  return x;
}
__device__ __forceinline__ float rsum16(float x) {
  x += dppmv<0x121>(x); x += dppmv<0x122>(x);
  x += dppmv<0x124>(x); x += dppmv<0x128>(x);
  return x;
}
#define MFMA(a,b,c) __builtin_amdgcn_mfma_f32_16x16x32_f16((a),(b),(c),0,0,0)

#define BARRIER() do { __builtin_amdgcn_s_barrier(); __builtin_amdgcn_sched_barrier(0); } while (0)
#define LGKM(n) do { asm volatile("s_waitcnt lgkmcnt(" #n ")" ::: "memory"); __builtin_amdgcn_sched_barrier(0); } while (0)
#define VMCNT(n) do { asm volatile("s_waitcnt vmcnt(" #n ")" ::: "memory"); __builtin_amdgcn_sched_barrier(0); } while (0)

// ---------------- fused pre-pass: fp32 -> fp16 for x, Wq, Wk, Wv, Wo ----------------
__global__ void k_cvt5(const float* __restrict__ x,
                       const float* __restrict__ Wq, const float* __restrict__ Wk,
                       const float* __restrict__ Wv, const float* __restrict__ Wo,
                       u16* __restrict__ xh, u16* __restrict__ wq, u16* __restrict__ wk,
                       u16* __restrict__ wv, u16* __restrict__ wo) {
  const int stride = gridDim.x * blockDim.x;
  for (int i = blockIdx.x * blockDim.x + threadIdx.x; i < 6291456; i += stride) {
    const float* s; u16* d; int j;
    if (i < 2097152) { s = x; d = xh; j = i; }
    else {
      const int t = (i - 2097152) >> 20;
      j = (i - 2097152) & 1048575;
      s = (t == 0) ? Wq : (t == 1) ? Wk : (t == 2) ? Wv : Wo;
      d = (t == 0) ? wq : (t == 1) ? wk : (t == 2) ? wv : wo;
    }
    const float4 v = ((const float4*)s)[j];
    ((ushort4*)d)[j] = make_ushort4(f2h(v.x), f2h(v.y), f2h(v.z), f2h(v.w));
  }
}

// ---------------- Q & K projection: fp16 single-pass, 256^2-tile, 8-phase ----------------
__global__ __launch_bounds__(512, 2) void gemm_qk(
    const u16* __restrict__ xh,
    const u16* __restrict__ wq, const u16* __restrict__ wk,
    u16* __restrict__ Qf, u16* __restrict__ Kf) {
  constexpr int NT = 32;  // 2048 / 64
  __shared__ __align__(16) char smem[131072];
  const int lin = blockIdx.x;
  const int z = lin >> 7;
  const int rr = lin & 127;
  const int n0 = (rr & 7) * 256;
  const int m0 = (rr >> 3) * 256;
  const u16* wgt = z ? wk : wq;
  u16* oq = z ? Kf : Qf;
  const int tid = threadIdx.x, wv = tid >> 6, ln = tid & 63;
  const int wvm = wv >> 2, wvn = wv & 3;

  auto stgA = [&](int tt, int par) {
    if (tt >= NT) return;
    const int kin = tt << 6;
    const int c = tt & 1;
    const int r8 = ln >> 3, cc = ((ln & 7) ^ r8) * 16;
#pragma unroll
    for (int e = 0; e < 2; ++e) {
      const int ch = e * 8 + wv;
      const int trow = (par + (ch >> 3) * 2) * 64 + (ch & 7) * 8;
      gll16((const char*)xh + (size_t)(m0 + trow + r8) * 4096 + (size_t)kin * 2 + cc,
            smem + c * 65536 + trow * 128);
    }
  };
  auto stgB = [&](int tt, int n2) {
    if (tt >= NT) return;
    const int kin = tt << 6;
    const int c = tt & 1;
    const int r8 = ln >> 3, cc = ((ln & 7) ^ r8) * 16;
#pragma unroll
    for (int e = 0; e < 2; ++e) {
      const int ch = e * 8 + wv;
      const int trow = (ch >> 2) * 64 + n2 * 32 + (ch & 3) * 8;
      gll16((const char*)wgt + (size_t)(n0 + trow + r8) * 4096 + (size_t)kin * 2 + cc,
            smem + c * 65536 + 32768 + trow * 128);
    }
  };
  auto ldAh = [&](int c, int h, half8 (*a)[2]) {
#pragma unroll
    for (int mm = 0; mm < 4; ++mm) {
      const int row = wvm * 128 + h * 64 + mm * 16 + (ln & 15);
#pragma unroll
      for (int s = 0; s < 2; ++s) {
        const int cb = (s * 64 + (ln >> 4) * 16) ^ ((row & 7) << 4);
        a[mm][s] = *(const half8*)(smem + c * 65536 + row * 128 + cb);
      }
    }
  };
  auto ldBh = [&](int c, int n2, half8 (*b)[2]) {
#pragma unroll
    for (int nn = 0; nn < 2; ++nn) {
      const int row = wvn * 64 + (n2 * 2 + nn) * 16 + (ln & 15);
#pragma unroll
      for (int s = 0; s < 2; ++s) {
        const int cb = (s * 64 + (ln >> 4) * 16) ^ ((row & 7) << 4);
        b[nn][s] = *(const half8*)(smem + c * 65536 + 32768 + row * 128 + cb);
      }
    }
  };

  const f32x4 fz = {0.f, 0.f, 0.f, 0.f};
  f32x4 acc[8][4];
#pragma unroll
  for (int mm = 0; mm < 8; ++mm)
#pragma unroll
    for (int nn = 0; nn < 4; ++nn) acc[mm][nn] = fz;

#define QUAD(MB, NB, AA, BB)                                                    \
  do {                                                                          \
    __builtin_amdgcn_s_setprio(1);                                              \
    _Pragma("unroll")                                                           \
    for (int mm = 0; mm < 4; ++mm)                                              \
      _Pragma("unroll")                                                         \
      for (int nn = 0; nn < 2; ++nn) {                                          \
        acc[MB + mm][NB + nn] = MFMA(AA[mm][0], BB[nn][0], acc[MB + mm][NB + nn]); \
        acc[MB + mm][NB + nn] = MFMA(AA[mm][1], BB[nn][1], acc[MB + mm][NB + nn]); \
      }                                                                         \
    __builtin_amdgcn_s_setprio(0);                                              \
  } while (0)

  stgA(0, 0); stgA(0, 1); stgB(0, 0); stgB(0, 1);
  stgA(1, 0); stgB(1, 0); stgB(1, 1);
  VMCNT(6);
  BARRIER();

  for (int w = 0; w < NT; ++w) {
    const int c = w & 1;
    half8 a[4][2], b0[2][2], b1[2][2];
    ldAh(c, 0, a);
    ldBh(c, 0, b0);
    stgA(w + 1, 1);
    BARRIER(); LGKM(0);
    QUAD(0, 0, a, b0);
    BARRIER();
    ldBh(c, 1, b1);
    stgA(w + 2, 0);
    BARRIER(); LGKM(0);
    QUAD(0, 2, a, b1);
    BARRIER();
    ldAh(c, 1, a);
    stgB(w + 2, 0);
    BARRIER(); LGKM(0);
    QUAD(4, 0, a, b0);
    BARRIER();
    stgB(w + 2, 1);
    BARRIER();
    QUAD(4, 2, a, b1);
    if (w + 2 < NT) { VMCNT(6); } else { VMCNT(0); }
    BARRIER();
  }
#undef QUAD

#pragma unroll
  for (int mm = 0; mm < 8; ++mm)
#pragma unroll
    for (int nn = 0; nn < 4; ++nn)
#pragma unroll
      for (int r4 = 0; r4 < 4; ++r4) {
        const int mg = m0 + wvm * 128 + mm * 16 + (ln >> 4) * 4 + r4;
        const int f = n0 + wvn * 64 + nn * 16 + (ln & 15);
        const int b = mg >> 11, s = mg & (Sd - 1);
        const int h = f >> 7, d = f & (Dd - 1);
        oq[(((size_t)b * Hd + h) * Sd + s) * Dd + d] = f2h(acc[mm][nn][r4]);
      }
}

// ---------------- single-pass fp16 GEMM, 128x256 tile, 4-phase pipeline ----------------
template<int MODE>
__global__ __launch_bounds__(512, 2) void gemm1(
    const u16* __restrict__ Ap, const u16* __restrict__ Bp,
    const float* __restrict__ bias, u16* __restrict__ ob, float* __restrict__ of) {
  constexpr int NT = 32;
  __shared__ __align__(16) char smem[98304];
  const int bid = blockIdx.x;
  const int n0 = (bid & 7) * 256;
  const int m0 = (bid >> 3) * 128;
  const int tid = threadIdx.x, wv = tid >> 6, ln = tid & 63;
  const int wvm = wv >> 2, wvn = wv & 3;

  auto stageA = [&](int tt, int c) {
    const int kin = tt << 6;
#pragma unroll
    for (int i = 0; i < 2; ++i) {
      const int l2 = i * 8192 + wv * 1024 + ln * 16;
      const int row = l2 >> 7, cb = l2 & 127;
      const int gc = cb ^ ((row & 7) << 4);
      gll16((const char*)Ap + (size_t)(m0 + row) * 4096 + (size_t)kin * 2 + gc,
            smem + c * 49152 + i * 8192 + wv * 1024);
    }
  };
  auto stageB = [&](int tt, int c) {
    const int kin = tt << 6;
#pragma unroll
    for (int i = 0; i < 4; ++i) {
      const int l2 = i * 8192 + wv * 1024 + ln * 16;
      const int row = l2 >> 7, cb = l2 & 127;
      const int gc = cb ^ ((row & 7) << 4);
      gll16((const char*)Bp + (size_t)(n0 + row) * 4096 + (size_t)kin * 2 + gc,
            smem + c * 49152 + 16384 + i * 8192 + wv * 1024);
    }
  };
  auto ldA = [&](int c, int s, half8* af) {
#pragma unroll
    for (int mm = 0; mm < 4; ++mm) {
      const int row = wvm * 64 + mm * 16 + (ln & 15);
      const int cb = (s * 64 + (ln >> 4) * 16) ^ ((row & 7) << 4);
      af[mm] = *(const half8*)(smem + c * 49152 + row * 128 + cb);
    }
  };
  auto ldB = [&](int c, int s, int p, half8* bf) {
#pragma unroll
    for (int j = 0; j < 2; ++j) {
      const int row = wvn * 64 + (p * 2 + j) * 16 + (ln & 15);
      const int cb = (s * 64 + (ln >> 4) * 16) ^ ((row & 7) << 4);
      bf[j] = *(const half8*)(smem + c * 49152 + 16384 + row * 128 + cb);
    }
  };

  const f32x4 fz = {0.f, 0.f, 0.f, 0.f};
  f32x4 acc[4][4];
#pragma unroll
  for (int mm = 0; mm < 4; ++mm)
#pragma unroll
    for (int nn = 0; nn < 4; ++nn) acc[mm][nn] = fz;

  stageA(0, 0);
  stageB(0, 0);
  stageA(1, 1);
  VMCNT(2);
  BARRIER();

  for (int t = 0; t < NT; ++t) {
    const int c = t & 1;
    const bool h1 = (t + 1 < NT), h2 = (t + 2 < NT);
    half8 af[4], bf01[2], bf23[2];
    ldA(c, 0, af);
    ldB(c, 0, 0, bf01);
    ldB(c, 0, 1, bf23);
    if (h1) stageB(t + 1, c ^ 1);
    BARRIER();
    LGKM(2);
    __builtin_amdgcn_s_setprio(1);
#pragma unroll
    for (int mm = 0; mm < 4; ++mm) {
      acc[mm][0] = MFMA(af[mm], bf01[0], acc[mm][0]);
      acc[mm][1] = MFMA(af[mm], bf01[1], acc[mm][1]);
    }
    __builtin_amdgcn_s_setprio(0);
    BARRIER();
    LGKM(0);
    __builtin_amdgcn_s_setprio(1);
#pragma unroll
    for (int mm = 0; mm < 4; ++mm) {
      acc[mm][2] = MFMA(af[mm], bf23[0], acc[mm][2]);
      acc[mm][3] = MFMA(af[mm], bf23[1], acc[mm][3]);
    }
    __builtin_amdgcn_s_setprio(0);
    BARRIER();
    ldA(c, 1, af);
    ldB(c, 1, 0, bf01);
    ldB(c, 1, 1, bf23);
    BARRIER();
    LGKM(2);
    __builtin_amdgcn_s_setprio(1);
#pragma unroll
    for (int mm = 0; mm < 4; ++mm) {
      acc[mm][0] = MFMA(af[mm], bf01[0], acc[mm][0]);
      acc[mm][1] = MFMA(af[mm], bf01[1], acc[mm][1]);
    }
    __builtin_amdgcn_s_setprio(0);
    BARRIER();
    if (h2) stageA(t + 2, c);
    LGKM(0);
    __builtin_amdgcn_s_setprio(1);
#pragma unroll
    for (int mm = 0; mm < 4; ++mm) {
      acc[mm][2] = MFMA(af[mm], bf23[0], acc[mm][2]);
      acc[mm][3] = MFMA(af[mm], bf23[1], acc[mm][3]);
    }
    __builtin_amdgcn_s_setprio(0);
    if (h2)      { VMCNT(2); }
    else if (h1) { VMCNT(0); }
    BARRIER();
  }

#pragma unroll
  for (int mm = 0; mm < 4; ++mm)
#pragma unroll
    for (int nn = 0; nn < 4; ++nn) {
      const int f = n0 + wvn * 64 + nn * 16 + (ln & 15);
      float bi = 0.f;
      if (MODE == 1) bi = bias[f];
#pragma unroll
      for (int r4 = 0; r4 < 4; ++r4) {
        const int mg = m0 + wvm * 64 + mm * 16 + (ln >> 4) * 4 + r4;
        if (MODE == 0) {
          const int b = mg >> 11, s = mg & (Sd - 1);
          const int h = f >> 7, d = f & (Dd - 1);
          ob[(((size_t)b * Hd + h) * Sd + s) * Dd + d] = f2h(acc[mm][nn][r4]);
        } else {
          of[(size_t)mg * Ed + f] = acc[mm][nn][r4] + bi;
        }
      }
    }
}

// ---------------- causal flash attention, split-KV (critical path <= 16 iters) ----------------
// y<8: direct tile qt=7-y (writes ctx). y in 8..15: (qt=y, half 0); y in 16..23:
// (qt=y-8, half 1) -> fp32 partials (acc,m,l), merged by k_comb. Per-CU trio = 34 iters.
__global__ __launch_bounds__(256, 3) void k_attn(
    const u16* __restrict__ Qf, const u16* __restrict__ Kf,
    const u16* __restrict__ Vb, u16* __restrict__ ctx,
    float* __restrict__ Op, float* __restrict__ ml) {
  __shared__ __align__(16) char smem[53248];
  char* KsB = smem;              // 16384 B  [64][128] f16, swizzled
  char* VtB = smem + 16384;      // 18432 B  [128 d][72 k] f16, swizzled
  char* PlB = smem + 34816;      // 18432 B  per-wave P slices

  const int bh = blockIdx.x;
  const int y = blockIdx.y;
  int qt, half;
  if (y < 8)       { qt = 7 - y;  half = -1; }
  else if (y < 16) { qt = y;      half = 0;  }
  else             { qt = y - 8;  half = 1;  }
  const int klo = (half == 1) ? (qt + 1) : 0;
  const int khi = (half == 0) ? (qt + 1) : (2 * qt + 2);
  const int tid = threadIdx.x, wv = tid >> 6, ln = tid & 63;
  const int q0 = qt * 128 + wv * 32;
  const size_t headoff = (size_t)bh * Sd * Dd;

  half8 qf[2][4];
#pragma unroll
  for (int mi = 0; mi < 2; ++mi)
#pragma unroll
    for (int c = 0; c < 4; ++c) {
      const size_t off = headoff + (size_t)(q0 + mi * 16 + (ln & 15)) * Dd + c * 32 + (ln >> 4) * 8;
      qf[mi][c] = *(const half8*)(Qf + off);
    }

  const f32x4 fz = {0.f, 0.f, 0.f, 0.f};
  f32x4 acc_o[2][8];
  float m_run[2][4], l_run[2][4];
#pragma unroll
  for (int mi = 0; mi < 2; ++mi) {
#pragma unroll
    for (int n = 0; n < 8; ++n) acc_o[mi][n] = fz;
#pragma unroll
    for (int r = 0; r < 4; ++r) { m_run[mi][r] = -1e30f; l_run[mi][r] = 0.f; }
  }

  for (int kt = klo; kt < khi; ++kt) {
    const size_t ktile = (headoff + (size_t)kt * 64 * Dd) * 2;
#pragma unroll
    for (int i = 0; i < 4; ++i) {
      const int lin = i * 4096 + wv * 1024 + ln * 16;
      const int row = lin >> 8;
      const int cb = lin & 255;
      const int gc = cb ^ ((row & 7) << 4);
      gll16((const char*)Kf + ktile + (size_t)row * 256 + gc, KsB + i * 4096 + wv * 1024);
    }
#pragma unroll
    for (int p = 0; p < 4; ++p) {
      const int rr = (tid >> 4) + 16 * p;
      const int d0 = (tid & 15) * 8;
      const ushort4 vv0 = *(const ushort4*)(Vb + headoff + (size_t)(kt * 64 + rr) * Dd + d0);
      const ushort4 vv1 = *(const ushort4*)(Vb + headoff + (size_t)(kt * 64 + rr) * Dd + d0 + 4);
      const u16 vs[8] = {vv0.x, vv0.y, vv0.z, vv0.w, vv1.x, vv1.y, vv1.z, vv1.w};
#pragma unroll
      for (int j = 0; j < 8; ++j) {
        const int d = d0 + j;
        *(u16*)(VtB + d * 144 + ((rr * 2) ^ (((d >> 3) & 7) << 4))) = vs[j];
      }
    }
    __syncthreads();

    const bool skip = (kt * 64) > (q0 + 31);

    f32x4 sc[2][4];
#pragma unroll
    for (int mi = 0; mi < 2; ++mi)
#pragma unroll
      for (int t = 0; t < 4; ++t) sc[mi][t] = fz;
    if (!skip) {
#pragma unroll
      for (int t = 0; t < 4; ++t)
#pragma unroll
        for (int c = 0; c < 4; ++c) {
          const int row = t * 16 + (ln & 15);
          const int cb = (c * 64 + (ln >> 4) * 16) ^ ((row & 7) << 4);
          const half8 kh8 = *(const half8*)(KsB + row * 256 + cb);
#pragma unroll
          for (int mi = 0; mi < 2; ++mi)
            sc[mi][t] = MFMA(qf[mi][c], kh8, sc[mi][t]);
        }
      if (kt >= 2 * qt) {
#pragma unroll
        for (int mi = 0; mi < 2; ++mi)
#pragma unroll
          for (int t = 0; t < 4; ++t)
#pragma unroll
            for (int r = 0; r < 4; ++r) {
              const int qg = q0 + mi * 16 + (ln >> 4) * 4 + r;
              const int kg = kt * 64 + t * 16 + (ln & 15);
              if (kg > qg) sc[mi][t][r] = -1e30f;
            }
      }

      // ---- online softmax (fp32, DPP row-reduce) + write P (fp16) to LDS ----
#pragma unroll
      for (int mi = 0; mi < 2; ++mi)
#pragma unroll
        for (int r = 0; r < 4; ++r) {
          float rm = fmaxf(fmaxf(sc[mi][0][r], sc[mi][1][r]),
                           fmaxf(sc[mi][2][r], sc[mi][3][r]));
          rm = rmax16(rm);
          const float mn = fmaxf(m_run[mi][r], rm);
          const float alpha = __expf(m_run[mi][r] - mn);
          m_run[mi][r] = mn;
          const int irow = mi * 16 + (ln >> 4) * 4 + r;
          float ps = 0.f;
#pragma unroll
          for (int t = 0; t < 4; ++t) {
            const float pv = __expf(sc[mi][t][r] - mn);
            ps += pv;
            *(u16*)(PlB + wv * 4608 + irow * 144 + (t * 16 + (ln & 15)) * 2) = f2h(pv);
          }
          ps = rsum16(ps);
          l_run[mi][r] = l_run[mi][r] * alpha + ps;
#pragma unroll
          for (int n = 0; n < 8; ++n) acc_o[mi][n][r] *= alpha;
        }
    }
    asm volatile("s_waitcnt lgkmcnt(0)" ::: "memory");
    __builtin_amdgcn_sched_barrier(0);

    if (!skip) {
      half8 pf[2][2];
#pragma unroll
      for (int mi = 0; mi < 2; ++mi)
#pragma unroll
        for (int c2 = 0; c2 < 2; ++c2)
          pf[mi][c2] = *(const half8*)(PlB + wv * 4608 + (mi * 16 + (ln & 15)) * 144 +
                                       c2 * 64 + (ln >> 4) * 16);
#pragma unroll
      for (int n = 0; n < 8; ++n)
#pragma unroll
        for (int c2 = 0; c2 < 2; ++c2) {
          const int d = n * 16 + (ln & 15);
          const half8 v8 = *(const half8*)(VtB + d * 144 +
                             ((c2 * 64 + (ln >> 4) * 16) ^ (((d >> 3) & 7) << 4)));
          acc_o[0][n] = MFMA(pf[0][c2], v8, acc_o[0][n]);
          acc_o[1][n] = MFMA(pf[1][c2], v8, acc_o[1][n]);
        }
    }
    __syncthreads();
  }

  if (half < 0) {
    // direct: normalize and write ctx (B,S,E) fp16
    const int b = bh >> 4, h = bh & 15;
#pragma unroll
    for (int mi = 0; mi < 2; ++mi)
#pragma unroll
      for (int r = 0; r < 4; ++r) {
        const float inv = 1.f / l_run[mi][r];
        const int s = q0 + mi * 16 + (ln >> 4) * 4 + r;
#pragma unroll
        for (int n = 0; n < 8; ++n) {
          const int col = n * 16 + (ln & 15);
          ctx[((size_t)b * Sd + s) * Ed + h * Dd + col] = f2h(acc_o[mi][n][r] * inv);
        }
      }
  } else {
    // partial: write unnormalized fp32 acc + (m,l) per row
    const int tile = bh * 8 + (qt - 8);
    const int pi = tile * 2 + half;
    const size_t ob = (size_t)pi * 16384;
#pragma unroll
    for (int mi = 0; mi < 2; ++mi)
#pragma unroll
      for (int r = 0; r < 4; ++r) {
        const int row = wv * 32 + mi * 16 + (ln >> 4) * 4 + r;
        if ((ln & 15) == 0) {
          ml[((size_t)pi * 128 + row) * 2 + 0] = m_run[mi][r];
          ml[((size_t)pi * 128 + row) * 2 + 1] = l_run[mi][r];
        }
#pragma unroll
        for (int n = 0; n < 8; ++n)
          Op[ob + (size_t)row * 128 + n * 16 + (ln & 15)] = acc_o[mi][n][r];
      }
  }
}

// ---------------- combine two KV-half partials -> ctx ----------------
__global__ __launch_bounds__(256) void k_comb(const float* __restrict__ Op,
                                              const float* __restrict__ ml,
                                              u16* __restrict__ ctx) {
  const int t = blockIdx.x;          // bh*8 + (qt-8)
  const int bh = t >> 3;
  const int qt = 8 + (t & 7);
  const int b = bh >> 4, h = bh & 15;
  const int tid = threadIdx.x;
  const int row = tid >> 1;
  const int d0 = (tid & 1) * 64;
  const float m1 = ml[((size_t)(t * 2 + 0) * 128 + row) * 2 + 0];
  const float l1 = ml[((size_t)(t * 2 + 0) * 128 + row) * 2 + 1];
  const float m2 = ml[((size_t)(t * 2 + 1) * 128 + row) * 2 + 0];
  const float l2 = ml[((size_t)(t * 2 + 1) * 128 + row) * 2 + 1];
  const float m = fmaxf(m1, m2);
  const float w1 = __expf(m1 - m), w2 = __expf(m2 - m);
  const float inv = 1.f / (w1 * l1 + w2 * l2);
  const float a1 = w1 * inv, a2 = w2 * inv;
  const size_t o1 = (size_t)(t * 2 + 0) * 16384 + (size_t)row * 128 + d0;
  const size_t o2 = (size_t)(t * 2 + 1) * 16384 + (size_t)row * 128 + d0;
  const int s = qt * 128 + row;
  u16* co = ctx + ((size_t)b * Sd + s) * Ed + h * Dd + d0;
#pragma unroll
  for (int j = 0; j < 16; ++j) {
    const float4 u = *(const float4*)(Op + o1 + j * 4);
    const float4 v = *(const float4*)(Op + o2 + j * 4);
    co[j * 4 + 0] = f2h(a1 * u.x + a2 * v.x);
    co[j * 4 + 1] = f2h(a1 * u.y + a2 * v.y);
    co[j * 4 + 2] = f2h(a1 * u.z + a2 * v.z);
    co[j * 4 + 3] = f2h(a1 * u.w + a2 * v.w);
  }
}

extern "C" void kernel_launch(void* const* d_in, const int* in_sizes, int n_in,
                              void* d_out, int out_size, void* d_ws, size_t ws_size,
                              hipStream_t stream) {
  (void)in_sizes; (void)n_in; (void)out_size; (void)ws_size;
  const float* x  = (const float*)d_in[0];
  const float* Wq = (const float*)d_in[1];
  const float* Wk = (const float*)d_in[2];
  const float* Wv = (const float*)d_in[3];
  const float* Wo = (const float*)d_in[4];
  const float* bo = (const float*)d_in[5];
  float* out = (float*)d_out;

  const size_t NTOK = (size_t)Bd * Sd * Ed;
  const size_t NW   = (size_t)Ed * Ed;

  char* w = (char*)d_ws;
  u16* xh  = (u16*)w; w += NTOK * 2;
  u16* wq  = (u16*)w; w += NW * 2;
  u16* wk  = (u16*)w; w += NW * 2;
  u16* wv  = (u16*)w; w += NW * 2;
  u16* wo  = (u16*)w; w += NW * 2;
  u16* Qf  = (u16*)w; w += NTOK * 2;
  u16* Kf  = (u16*)w; w += NTOK * 2;
  u16* Vf  = (u16*)w; w += NTOK * 2;
  u16* ctx = (u16*)w; w += NTOK * 2;
  float* Op = (float*)w; w += (size_t)512 * 16384 * 4;   // 32 MB partials
  float* ml = (float*)w; w += (size_t)512 * 128 * 2 * 4; // 0.5 MB (m,l)

  k_cvt5<<<dim3(2048), 256, 0, stream>>>(x, Wq, Wk, Wv, Wo, xh, wq, wk, wv, wo);

  gemm_qk<<<dim3(256), 512, 0, stream>>>(xh, wq, wk, Qf, Kf);
  gemm1<0><<<dim3(256), 512, 0, stream>>>(xh, wv, nullptr, Vf, nullptr);

  k_attn<<<dim3(Bd * Hd, 24), 256, 0, stream>>>(Qf, Kf, Vf, ctx, Op, ml);
  k_comb<<<dim3(256), 256, 0, stream>>>(Op, ml, ctx);

  gemm1<1><<<dim3(256), 512, 0, stream>>>(ctx, wo, bo, nullptr, out);
}

// Round 11
// 254.916 us; speedup vs baseline: 1.3133x; 1.3133x over previous
//
#include <hip/hip_runtime.h>
#include <stdint.h>
#include <stddef.h>

#define Bd 2
#define Sd 2048
#define Ed 2048
#define Hd 16
#define Dd 128

typedef unsigned short u16;
typedef _Float16 f16;
typedef __attribute__((ext_vector_type(8))) _Float16 half8;
typedef __attribute__((ext_vector_type(4))) float f32x4;

__device__ __forceinline__ u16 f2h(float f) {
  f16 h = (f16)f; return __builtin_bit_cast(u16, h);
}
__device__ __forceinline__ void gll16(const void* g, void* lds) {
  __builtin_amdgcn_global_load_lds(
      (const __attribute__((address_space(1))) void*)g,
      (__attribute__((address_space(3))) void*)lds, 16, 0, 0);
}
template<int C> __device__ __forceinline__ float dppmv(float x) {
  return __builtin_bit_cast(float,
      __builtin_amdgcn_update_dpp(0, __builtin_bit_cast(int, x), C, 0xF, 0xF, false));
}
__device__ __forceinline__ float rmax16(float x) {
  x = fmaxf(x, dppmv<0x121>(x)); x = fmaxf(x, dppmv<0x122>(x));
  x = fmaxf(x, dppmv<0x124>(x)); x = fmaxf(x, dppmv<0x128>(x));
  return x;
}
__device__ __forceinline__ float rsum16(float x) {
  x += dppmv<0x121>(x); x += dppmv<0x122>(x);
  x += dppmv<0x124>(x); x += dppmv<0x128>(x);
  return x;
}
#define MFMA(a,b,c) __builtin_amdgcn_mfma_f32_16x16x32_f16((a),(b),(c),0,0,0)

#define BARRIER() do { __builtin_amdgcn_s_barrier(); __builtin_amdgcn_sched_barrier(0); } while (0)
#define LGKM(n) do { asm volatile("s_waitcnt lgkmcnt(" #n ")" ::: "memory"); __builtin_amdgcn_sched_barrier(0); } while (0)
#define VMCNT(n) do { asm volatile("s_waitcnt vmcnt(" #n ")" ::: "memory"); __builtin_amdgcn_sched_barrier(0); } while (0)

// ---------------- fused pre-pass: fp32 -> fp16 for x, Wq, Wk, Wv, Wo ----------------
__global__ void k_cvt5(const float* __restrict__ x,
                       const float* __restrict__ Wq, const float* __restrict__ Wk,
                       const float* __restrict__ Wv, const float* __restrict__ Wo,
                       u16* __restrict__ xh, u16* __restrict__ wq, u16* __restrict__ wk,
                       u16* __restrict__ wv, u16* __restrict__ wo) {
  const int stride = gridDim.x * blockDim.x;
  for (int i = blockIdx.x * blockDim.x + threadIdx.x; i < 6291456; i += stride) {
    const float* s; u16* d; int j;
    if (i < 2097152) { s = x; d = xh; j = i; }
    else {
      const int t = (i - 2097152) >> 20;
      j = (i - 2097152) & 1048575;
      s = (t == 0) ? Wq : (t == 1) ? Wk : (t == 2) ? Wv : Wo;
      d = (t == 0) ? wq : (t == 1) ? wk : (t == 2) ? wv : wo;
    }
    const float4 v = ((const float4*)s)[j];
    ((ushort4*)d)[j] = make_ushort4(f2h(v.x), f2h(v.y), f2h(v.z), f2h(v.w));
  }
}

// ---------------- Q & K projection: fp16 single-pass, 256^2-tile, 8-phase ----------------
__global__ __launch_bounds__(512, 2) void gemm_qk(
    const u16* __restrict__ xh,
    const u16* __restrict__ wq, const u16* __restrict__ wk,
    u16* __restrict__ Qf, u16* __restrict__ Kf) {
  constexpr int NT = 32;  // 2048 / 64
  __shared__ __align__(16) char smem[131072];
  const int lin = blockIdx.x;
  const int z = lin >> 7;
  const int rr = lin & 127;
  const int n0 = (rr & 7) * 256;
  const int m0 = (rr >> 3) * 256;
  const u16* wgt = z ? wk : wq;
  u16* oq = z ? Kf : Qf;
  const int tid = threadIdx.x, wv = tid >> 6, ln = tid & 63;
  const int wvm = wv >> 2, wvn = wv & 3;

  auto stgA = [&](int tt, int par) {
    if (tt >= NT) return;
    const int kin = tt << 6;
    const int c = tt & 1;
    const int r8 = ln >> 3, cc = ((ln & 7) ^ r8) * 16;
#pragma unroll
    for (int e = 0; e < 2; ++e) {
      const int ch = e * 8 + wv;
      const int trow = (par + (ch >> 3) * 2) * 64 + (ch & 7) * 8;
      gll16((const char*)xh + (size_t)(m0 + trow + r8) * 4096 + (size_t)kin * 2 + cc,
            smem + c * 65536 + trow * 128);
    }
  };
  auto stgB = [&](int tt, int n2) {
    if (tt >= NT) return;
    const int kin = tt << 6;
    const int c = tt & 1;
    const int r8 = ln >> 3, cc = ((ln & 7) ^ r8) * 16;
#pragma unroll
    for (int e = 0; e < 2; ++e) {
      const int ch = e * 8 + wv;
      const int trow = (ch >> 2) * 64 + n2 * 32 + (ch & 3) * 8;
      gll16((const char*)wgt + (size_t)(n0 + trow + r8) * 4096 + (size_t)kin * 2 + cc,
            smem + c * 65536 + 32768 + trow * 128);
    }
  };
  auto ldAh = [&](int c, int h, half8 (*a)[2]) {
#pragma unroll
    for (int mm = 0; mm < 4; ++mm) {
      const int row = wvm * 128 + h * 64 + mm * 16 + (ln & 15);
#pragma unroll
      for (int s = 0; s < 2; ++s) {
        const int cb = (s * 64 + (ln >> 4) * 16) ^ ((row & 7) << 4);
        a[mm][s] = *(const half8*)(smem + c * 65536 + row * 128 + cb);
      }
    }
  };
  auto ldBh = [&](int c, int n2, half8 (*b)[2]) {
#pragma unroll
    for (int nn = 0; nn < 2; ++nn) {
      const int row = wvn * 64 + (n2 * 2 + nn) * 16 + (ln & 15);
#pragma unroll
      for (int s = 0; s < 2; ++s) {
        const int cb = (s * 64 + (ln >> 4) * 16) ^ ((row & 7) << 4);
        b[nn][s] = *(const half8*)(smem + c * 65536 + 32768 + row * 128 + cb);
      }
    }
  };

  const f32x4 fz = {0.f, 0.f, 0.f, 0.f};
  f32x4 acc[8][4];
#pragma unroll
  for (int mm = 0; mm < 8; ++mm)
#pragma unroll
    for (int nn = 0; nn < 4; ++nn) acc[mm][nn] = fz;

#define QUAD(MB, NB, AA, BB)                                                    \
  do {                                                                          \
    __builtin_amdgcn_s_setprio(1);                                              \
    _Pragma("unroll")                                                           \
    for (int mm = 0; mm < 4; ++mm)                                              \
      _Pragma("unroll")                                                         \
      for (int nn = 0; nn < 2; ++nn) {                                          \
        acc[MB + mm][NB + nn] = MFMA(AA[mm][0], BB[nn][0], acc[MB + mm][NB + nn]); \
        acc[MB + mm][NB + nn] = MFMA(AA[mm][1], BB[nn][1], acc[MB + mm][NB + nn]); \
      }                                                                         \
    __builtin_amdgcn_s_setprio(0);                                              \
  } while (0)

  stgA(0, 0); stgA(0, 1); stgB(0, 0); stgB(0, 1);
  stgA(1, 0); stgB(1, 0); stgB(1, 1);
  VMCNT(6);
  BARRIER();

  for (int w = 0; w < NT; ++w) {
    const int c = w & 1;
    half8 a[4][2], b0[2][2], b1[2][2];
    ldAh(c, 0, a);
    ldBh(c, 0, b0);
    stgA(w + 1, 1);
    BARRIER(); LGKM(0);
    QUAD(0, 0, a, b0);
    BARRIER();
    ldBh(c, 1, b1);
    stgA(w + 2, 0);
    BARRIER(); LGKM(0);
    QUAD(0, 2, a, b1);
    BARRIER();
    ldAh(c, 1, a);
    stgB(w + 2, 0);
    BARRIER(); LGKM(0);
    QUAD(4, 0, a, b0);
    BARRIER();
    stgB(w + 2, 1);
    BARRIER();
    QUAD(4, 2, a, b1);
    if (w + 2 < NT) { VMCNT(6); } else { VMCNT(0); }
    BARRIER();
  }
#undef QUAD

#pragma unroll
  for (int mm = 0; mm < 8; ++mm)
#pragma unroll
    for (int nn = 0; nn < 4; ++nn)
#pragma unroll
      for (int r4 = 0; r4 < 4; ++r4) {
        const int mg = m0 + wvm * 128 + mm * 16 + (ln >> 4) * 4 + r4;
        const int f = n0 + wvn * 64 + nn * 16 + (ln & 15);
        const int b = mg >> 11, s = mg & (Sd - 1);
        const int h = f >> 7, d = f & (Dd - 1);
        oq[(((size_t)b * Hd + h) * Sd + s) * Dd + d] = f2h(acc[mm][nn][r4]);
      }
}

// ---------------- single-pass fp16 GEMM, 128x256 tile, 4-phase pipeline ----------------
template<int MODE>
__global__ __launch_bounds__(512, 2) void gemm1(
    const u16* __restrict__ Ap, const u16* __restrict__ Bp,
    const float* __restrict__ bias, u16* __restrict__ ob, float* __restrict__ of) {
  constexpr int NT = 32;
  __shared__ __align__(16) char smem[98304];
  const int bid = blockIdx.x;
  const int n0 = (bid & 7) * 256;
  const int m0 = (bid >> 3) * 128;
  const int tid = threadIdx.x, wv = tid >> 6, ln = tid & 63;
  const int wvm = wv >> 2, wvn = wv & 3;

  auto stageA = [&](int tt, int c) {
    const int kin = tt << 6;
#pragma unroll
    for (int i = 0; i < 2; ++i) {
      const int l2 = i * 8192 + wv * 1024 + ln * 16;
      const int row = l2 >> 7, cb = l2 & 127;
      const int gc = cb ^ ((row & 7) << 4);
      gll16((const char*)Ap + (size_t)(m0 + row) * 4096 + (size_t)kin * 2 + gc,
            smem + c * 49152 + i * 8192 + wv * 1024);
    }
  };
  auto stageB = [&](int tt, int c) {
    const int kin = tt << 6;
#pragma unroll
    for (int i = 0; i < 4; ++i) {
      const int l2 = i * 8192 + wv * 1024 + ln * 16;
      const int row = l2 >> 7, cb = l2 & 127;
      const int gc = cb ^ ((row & 7) << 4);
      gll16((const char*)Bp + (size_t)(n0 + row) * 4096 + (size_t)kin * 2 + gc,
            smem + c * 49152 + 16384 + i * 8192 + wv * 1024);
    }
  };
  auto ldA = [&](int c, int s, half8* af) {
#pragma unroll
    for (int mm = 0; mm < 4; ++mm) {
      const int row = wvm * 64 + mm * 16 + (ln & 15);
      const int cb = (s * 64 + (ln >> 4) * 16) ^ ((row & 7) << 4);
      af[mm] = *(const half8*)(smem + c * 49152 + row * 128 + cb);
    }
  };
  auto ldB = [&](int c, int s, int p, half8* bf) {
#pragma unroll
    for (int j = 0; j < 2; ++j) {
      const int row = wvn * 64 + (p * 2 + j) * 16 + (ln & 15);
      const int cb = (s * 64 + (ln >> 4) * 16) ^ ((row & 7) << 4);
      bf[j] = *(const half8*)(smem + c * 49152 + 16384 + row * 128 + cb);
    }
  };

  const f32x4 fz = {0.f, 0.f, 0.f, 0.f};
  f32x4 acc[4][4];
#pragma unroll
  for (int mm = 0; mm < 4; ++mm)
#pragma unroll
    for (int nn = 0; nn < 4; ++nn) acc[mm][nn] = fz;

  stageA(0, 0);
  stageB(0, 0);
  stageA(1, 1);
  VMCNT(2);
  BARRIER();

  for (int t = 0; t < NT; ++t) {
    const int c = t & 1;
    const bool h1 = (t + 1 < NT), h2 = (t + 2 < NT);
    half8 af[4], bf01[2], bf23[2];
    ldA(c, 0, af);
    ldB(c, 0, 0, bf01);
    ldB(c, 0, 1, bf23);
    if (h1) stageB(t + 1, c ^ 1);
    BARRIER();
    LGKM(2);
    __builtin_amdgcn_s_setprio(1);
#pragma unroll
    for (int mm = 0; mm < 4; ++mm) {
      acc[mm][0] = MFMA(af[mm], bf01[0], acc[mm][0]);
      acc[mm][1] = MFMA(af[mm], bf01[1], acc[mm][1]);
    }
    __builtin_amdgcn_s_setprio(0);
    BARRIER();
    LGKM(0);
    __builtin_amdgcn_s_setprio(1);
#pragma unroll
    for (int mm = 0; mm < 4; ++mm) {
      acc[mm][2] = MFMA(af[mm], bf23[0], acc[mm][2]);
      acc[mm][3] = MFMA(af[mm], bf23[1], acc[mm][3]);
    }
    __builtin_amdgcn_s_setprio(0);
    BARRIER();
    ldA(c, 1, af);
    ldB(c, 1, 0, bf01);
    ldB(c, 1, 1, bf23);
    BARRIER();
    LGKM(2);
    __builtin_amdgcn_s_setprio(1);
#pragma unroll
    for (int mm = 0; mm < 4; ++mm) {
      acc[mm][0] = MFMA(af[mm], bf01[0], acc[mm][0]);
      acc[mm][1] = MFMA(af[mm], bf01[1], acc[mm][1]);
    }
    __builtin_amdgcn_s_setprio(0);
    BARRIER();
    if (h2) stageA(t + 2, c);
    LGKM(0);
    __builtin_amdgcn_s_setprio(1);
#pragma unroll
    for (int mm = 0; mm < 4; ++mm) {
      acc[mm][2] = MFMA(af[mm], bf23[0], acc[mm][2]);
      acc[mm][3] = MFMA(af[mm], bf23[1], acc[mm][3]);
    }
    __builtin_amdgcn_s_setprio(0);
    if (h2)      { VMCNT(2); }
    else if (h1) { VMCNT(0); }
    BARRIER();
  }

#pragma unroll
  for (int mm = 0; mm < 4; ++mm)
#pragma unroll
    for (int nn = 0; nn < 4; ++nn) {
      const int f = n0 + wvn * 64 + nn * 16 + (ln & 15);
      float bi = 0.f;
      if (MODE == 1) bi = bias[f];
#pragma unroll
      for (int r4 = 0; r4 < 4; ++r4) {
        const int mg = m0 + wvm * 64 + mm * 16 + (ln >> 4) * 4 + r4;
        if (MODE == 0) {
          const int b = mg >> 11, s = mg & (Sd - 1);
          const int h = f >> 7, d = f & (Dd - 1);
          ob[(((size_t)b * Hd + h) * Sd + s) * Dd + d] = f2h(acc[mm][nn][r4]);
        } else {
          of[(size_t)mg * Ed + f] = acc[mm][nn][r4] + bi;
        }
      }
    }
}

// ---------------- causal flash attention, KVBLK=128 (deepest block 16 iters) ----------------
// Row strides 272 B (=17x16: all half8 reads 16B-aligned); swizzle (row&7)<<4 only.
// qt = 15-y: long blocks queued desc first, then short desc -> every CU ~17 iters.
__global__ __launch_bounds__(256, 1) void k_attn(
    const u16* __restrict__ Qf, const u16* __restrict__ Kf,
    const u16* __restrict__ Vb, u16* __restrict__ ctx) {
  __shared__ __align__(16) char smem[102400];
  char* KsB = smem;            // 32768 B  [128 k][256 B] f16, swizzled
  char* VtB = smem + 32768;    // 34816 B  [128 d][272 B] f16, swizzled
  char* PlB = smem + 67584;    // 34816 B  4 x [32 q][272 B]

  const int bh = blockIdx.x;
  const int qt = 15 - (int)blockIdx.y;
  const int tid = threadIdx.x, wv = tid >> 6, ln = tid & 63;
  const int q0 = qt * 128 + wv * 32;
  const size_t headoff = (size_t)bh * Sd * Dd;

  half8 qf[2][4];
#pragma unroll
  for (int mi = 0; mi < 2; ++mi)
#pragma unroll
    for (int c = 0; c < 4; ++c) {
      const size_t off = headoff + (size_t)(q0 + mi * 16 + (ln & 15)) * Dd + c * 32 + (ln >> 4) * 8;
      qf[mi][c] = *(const half8*)(Qf + off);
    }

  const f32x4 fz = {0.f, 0.f, 0.f, 0.f};
  f32x4 acc_o[2][8];
  float m_run[2][4], l_run[2][4];
#pragma unroll
  for (int mi = 0; mi < 2; ++mi) {
#pragma unroll
    for (int n = 0; n < 8; ++n) acc_o[mi][n] = fz;
#pragma unroll
    for (int r = 0; r < 4; ++r) { m_run[mi][r] = -1e30f; l_run[mi][r] = 0.f; }
  }

  for (int kt = 0; kt <= qt; ++kt) {
    // ---- stage K [128][128] f16 via gll16 (pre-swizzled source) ----
    const size_t ktile = (headoff + (size_t)kt * 128 * Dd) * 2;
#pragma unroll
    for (int i = 0; i < 8; ++i) {
      const int l2 = i * 4096 + wv * 1024 + ln * 16;
      const int row = l2 >> 8;
      const int cb = l2 & 255;
      const int gc = cb ^ ((row & 7) << 4);
      gll16((const char*)Kf + ktile + (size_t)row * 256 + gc, KsB + i * 4096 + wv * 1024);
    }
    // ---- V transpose: hoisted loads, then scatter writes ----
    uint4 vp[8];
#pragma unroll
    for (int p = 0; p < 8; ++p) {
      const int rr = (tid >> 4) + 16 * p;
      vp[p] = *(const uint4*)(Vb + headoff + (size_t)(kt * 128 + rr) * Dd + (tid & 15) * 8);
    }
#pragma unroll
    for (int p = 0; p < 8; ++p) {
      const int rr = (tid >> 4) + 16 * p;
      const int d0 = (tid & 15) * 8;
      const u16 vs[8] = {(u16)(vp[p].x & 0xffff), (u16)(vp[p].x >> 16),
                         (u16)(vp[p].y & 0xffff), (u16)(vp[p].y >> 16),
                         (u16)(vp[p].z & 0xffff), (u16)(vp[p].z >> 16),
                         (u16)(vp[p].w & 0xffff), (u16)(vp[p].w >> 16)};
#pragma unroll
      for (int j = 0; j < 8; ++j) {
        const int d = d0 + j;
        *(u16*)(VtB + d * 272 + ((rr * 2) ^ (((d >> 3) & 7) << 4))) = vs[j];
      }
    }
    __syncthreads();

    // ---- scores: S = Q K^T over 128 kv cols ----
    f32x4 sc[2][8];
#pragma unroll
    for (int mi = 0; mi < 2; ++mi)
#pragma unroll
      for (int t = 0; t < 8; ++t) sc[mi][t] = fz;
#pragma unroll
    for (int t = 0; t < 8; ++t)
#pragma unroll
      for (int c = 0; c < 4; ++c) {
        const int row = t * 16 + (ln & 15);
        const int cb = (c * 64 + (ln >> 4) * 16) ^ ((row & 7) << 4);
        const half8 kh8 = *(const half8*)(KsB + row * 256 + cb);
        sc[0][t] = MFMA(qf[0][c], kh8, sc[0][t]);
        sc[1][t] = MFMA(qf[1][c], kh8, sc[1][t]);
      }
    if (kt == qt) {  // diagonal 128-block: causal mask
#pragma unroll
      for (int mi = 0; mi < 2; ++mi)
#pragma unroll
        for (int t = 0; t < 8; ++t)
#pragma unroll
          for (int r = 0; r < 4; ++r) {
            const int qg = q0 + mi * 16 + (ln >> 4) * 4 + r;
            const int kg = kt * 128 + t * 16 + (ln & 15);
            if (kg > qg) sc[mi][t][r] = -1e30f;
          }
    }

    // ---- online softmax (fp32, DPP row-reduce) + write P (fp16) to LDS ----
#pragma unroll
    for (int mi = 0; mi < 2; ++mi)
#pragma unroll
      for (int r = 0; r < 4; ++r) {
        float rm = fmaxf(fmaxf(fmaxf(sc[mi][0][r], sc[mi][1][r]),
                               fmaxf(sc[mi][2][r], sc[mi][3][r])),
                         fmaxf(fmaxf(sc[mi][4][r], sc[mi][5][r]),
                               fmaxf(sc[mi][6][r], sc[mi][7][r])));
        rm = rmax16(rm);
        const float mn = fmaxf(m_run[mi][r], rm);
        const float alpha = __expf(m_run[mi][r] - mn);
        m_run[mi][r] = mn;
        const int irow = mi * 16 + (ln >> 4) * 4 + r;
        float ps = 0.f;
#pragma unroll
        for (int t = 0; t < 8; ++t) {
          const float pv = __expf(sc[mi][t][r] - mn);
          ps += pv;
          *(u16*)(PlB + wv * 8704 + irow * 272 + (t * 16 + (ln & 15)) * 2) = f2h(pv);
        }
        ps = rsum16(ps);
        l_run[mi][r] = l_run[mi][r] * alpha + ps;
#pragma unroll
        for (int n = 0; n < 8; ++n) acc_o[mi][n][r] *= alpha;
      }
    asm volatile("s_waitcnt lgkmcnt(0)" ::: "memory");
    __builtin_amdgcn_sched_barrier(0);

    // ---- PV: O += P * V (k = 128 -> 4 k-slots) ----
    half8 pf[2][4];
#pragma unroll
    for (int mi = 0; mi < 2; ++mi)
#pragma unroll
      for (int c2 = 0; c2 < 4; ++c2)
        pf[mi][c2] = *(const half8*)(PlB + wv * 8704 + (mi * 16 + (ln & 15)) * 272 +
                                     c2 * 64 + (ln >> 4) * 16);
#pragma unroll
    for (int n = 0; n < 8; ++n)
#pragma unroll
      for (int c2 = 0; c2 < 4; ++c2) {
        const int d = n * 16 + (ln & 15);
        const half8 v8 = *(const half8*)(VtB + d * 272 +
                           ((c2 * 64 + (ln >> 4) * 16) ^ (((d >> 3) & 7) << 4)));
        acc_o[0][n] = MFMA(pf[0][c2], v8, acc_o[0][n]);
        acc_o[1][n] = MFMA(pf[1][c2], v8, acc_o[1][n]);
      }
    __syncthreads();
  }

  // ---- epilogue: normalize, write ctx (B,S,E) fp16 ----
  const int b = bh >> 4, h = bh & 15;
#pragma unroll
  for (int mi = 0; mi < 2; ++mi)
#pragma unroll
    for (int r = 0; r < 4; ++r) {
      const float inv = 1.f / l_run[mi][r];
      const int s = q0 + mi * 16 + (ln >> 4) * 4 + r;
#pragma unroll
      for (int n = 0; n < 8; ++n) {
        const int col = n * 16 + (ln & 15);
        ctx[((size_t)b * Sd + s) * Ed + h * Dd + col] = f2h(acc_o[mi][n][r] * inv);
      }
    }
}

extern "C" void kernel_launch(void* const* d_in, const int* in_sizes, int n_in,
                              void* d_out, int out_size, void* d_ws, size_t ws_size,
                              hipStream_t stream) {
  (void)in_sizes; (void)n_in; (void)out_size; (void)ws_size;
  const float* x  = (const float*)d_in[0];
  const float* Wq = (const float*)d_in[1];
  const float* Wk = (const float*)d_in[2];
  const float* Wv = (const float*)d_in[3];
  const float* Wo = (const float*)d_in[4];
  const float* bo = (const float*)d_in[5];
  float* out = (float*)d_out;

  const size_t NTOK = (size_t)Bd * Sd * Ed;
  const size_t NW   = (size_t)Ed * Ed;

  char* w = (char*)d_ws;
  u16* xh  = (u16*)w; w += NTOK * 2;
  u16* wq  = (u16*)w; w += NW * 2;
  u16* wk  = (u16*)w; w += NW * 2;
  u16* wv  = (u16*)w; w += NW * 2;
  u16* wo  = (u16*)w; w += NW * 2;
  u16* Qf  = (u16*)w; w += NTOK * 2;
  u16* Kf  = (u16*)w; w += NTOK * 2;
  u16* Vf  = (u16*)w; w += NTOK * 2;
  u16* ctx = (u16*)w; w += NTOK * 2;

  k_cvt5<<<dim3(2048), 256, 0, stream>>>(x, Wq, Wk, Wv, Wo, xh, wq, wk, wv, wo);

  gemm_qk<<<dim3(256), 512, 0, stream>>>(xh, wq, wk, Qf, Kf);
  gemm1<0><<<dim3(256), 512, 0, stream>>>(xh, wv, nullptr, Vf, nullptr);

  k_attn<<<dim3(Bd * Hd, 16), 256, 0, stream>>>(Qf, Kf, Vf, ctx);

  gemm1<1><<<dim3(256), 512, 0, stream>>>(ctx, wo, bo, nullptr, out);
}